// Round 4
// baseline (203.809 us; speedup 1.0000x reference)
//
#include <hip/hip_runtime.h>
#include <hip/hip_bf16.h>
#include <math.h>

// Masked dot-product attention, bf16 MFMA flash kernel, round 7.
// B=32, LQ=LK=2048, D=64. S^T = K*Q^T and O^T = V^T*P^T with 32x32x16 MFMA.
// NEW vs round 6: 4 q-waves per block SHARING one 32KB K/V staging pipeline.
//  - Round-6 post-mortem: ~33.8k wave-tiles at ~1.3 waves/SIMD ran at raw
//    dependent-chain latency (~8k cyc/tile). Binding constraint = resident
//    waves/SIMD (LDS-bound: 5 blocks x 2 waves). Same LDS with 4 q-waves
//    doubles the wave cap (16/CU, VGPR-bound) and halves per-thread staging.
//  - Cross-block KV split (NS=4) + merge kernel retained from round 6.

#define B_    32
#define LQ_   2048
#define LK_   2048
#define D_    64

typedef __attribute__((ext_vector_type(8)))  short bf16x8;
typedef __attribute__((ext_vector_type(4)))  float f32x4;
typedef __attribute__((ext_vector_type(16))) float f32x16;

static __device__ __forceinline__ unsigned pk_bf16(float a, float b) {
    __hip_bfloat162 h = __float22bfloat162_rn(float2{a, b});
    return *(unsigned*)&h;   // x in low 16 bits, y in high
}

// ---------------------------------------------------------------------------
// Pass 1: per-(qblock=128 rows, batch, split) flash attention over [t0, t1).
// 256 threads = 4 q-waves sharing one double-buffered 64x64 K/V LDS tile.
// Writes UNNORMALIZED O^T partial + (m, l) per q row.
// ---------------------------------------------------------------------------
__global__ __launch_bounds__(256, 4) void fa_split2_kernel(
    const float* __restrict__ Q, const float* __restrict__ K,
    const float* __restrict__ V, const int* __restrict__ vlen,
    float* __restrict__ OP, float* __restrict__ ML)
{
    __shared__ __align__(16) short Kl[2][64 * 64];
    __shared__ __align__(16) short Vt[2][64 * 64];

    const int tid  = threadIdx.x;          // 0..255
    const int wid  = tid >> 6;             // 0..3  (q sub-block)
    const int lane = tid & 63;
    const int c31  = lane & 31;
    const int h    = lane >> 5;

    const int b  = blockIdx.y;
    const int s  = blockIdx.z;
    const int NS = gridDim.z;
    const int q0 = blockIdx.x * 128 + wid * 32;
    const int vl = vlen[b];
    const int nt    = (vl + 63) >> 6;
    const int chunk = (nt + NS - 1) / NS;
    const int t0    = s * chunk;
    const int t1    = min(t0 + chunk, nt);

    const float qscale = 0.125f * 1.44269504088896340736f;  // 1/sqrt(64)*log2(e)

    // ---- Q B-frags in registers: B[k=dim][n=q], dim = ks*16 + h*8 + j ----
    unsigned qfrag[4][4];
#pragma unroll
    for (int ks = 0; ks < 4; ++ks) {
        const float* qp = Q + ((size_t)(b * LQ_ + q0 + c31)) * D_ + ks * 16 + h * 8;
        f32x4 t0v = *(const f32x4*)qp;
        f32x4 t1v = *(const f32x4*)(qp + 4);
#pragma unroll
        for (int jj = 0; jj < 2; ++jj) {
            qfrag[ks][jj]     = pk_bf16(t0v[2*jj] * qscale, t0v[2*jj+1] * qscale);
            qfrag[ks][jj + 2] = pk_bf16(t1v[2*jj] * qscale, t1v[2*jj+1] * qscale);
        }
    }

    f32x16 oacc[2];     // O^T acc: dim row = dt*32 + (r&3)+8*(r>>2)+4h, col q = c31
#pragma unroll
    for (int dt = 0; dt < 2; ++dt)
#pragma unroll
        for (int r = 0; r < 16; ++r) oacc[dt][r] = 0.f;
    float mrun = -INFINITY, lrun = 0.f;

    // ---- staging maps (256 threads stage the whole 64x64 K and V tiles) ----
    // K: row skey (0..63), quarter skh (0..3) of 16 floats.
    const int skey = tid >> 2, skh = tid & 3;
    // V: keys vkg*4..+3 (vkg 0..15), dims vdg*4..+3 (vdg 0..15).
    const int vkg = tid >> 4, vdg = tid & 15;

    const float* kgp = K + ((size_t)(b * LK_ + skey)) * D_ + skh * 16;
    const float* vgp = V + ((size_t)(b * LK_ + vkg * 4)) * D_ + vdg * 4;

    f32x4 kr[4], vr[4];
    // ---- prologue: prefetch tile t0 into registers ----
    if (t0 < t1) {
        const size_t off = (size_t)t0 * 64 * D_;
#pragma unroll
        for (int i = 0; i < 4; ++i) kr[i] = *(const f32x4*)(kgp + off + 4 * i);
#pragma unroll
        for (int i = 0; i < 4; ++i) vr[i] = *(const f32x4*)(vgp + off + (size_t)i * D_);
    }

    for (int t = t0; t < t1; ++t) {
        const int k0 = t * 64;
        const int buf = t & 1;

        // ---- cvt + write tile t to LDS ----
        {
            // K: 16 floats -> 8 packed pairs -> 2 swizzled b128 writes
            unsigned pk32[8];
#pragma unroll
            for (int m = 0; m < 8; ++m)
                pk32[m] = pk_bf16(kr[m >> 1][2 * (m & 1)], kr[m >> 1][2 * (m & 1) + 1]);
#pragma unroll
            for (int cch = 0; cch < 2; ++cch) {
                const int pos = (skh * 2 + cch) ^ (skey & 7);
                *(bf16x8*)&Kl[buf][skey * 64 + pos * 8] = *(bf16x8*)&pk32[4 * cch];
            }
            // V^T: 4 keys x 4 dims -> per dim one 8B write (half of a 16B chunk)
#pragma unroll
            for (int dr = 0; dr < 4; ++dr) {
                const unsigned w0 = pk_bf16(vr[0][dr], vr[1][dr]);
                const unsigned w1 = pk_bf16(vr[2][dr], vr[3][dr]);
                const int dim = vdg * 4 + dr;
                const int pos = (vkg >> 1) ^ (dim & 7);
                uint2* dst = (uint2*)&Vt[buf][dim * 64 + pos * 8 + (vkg & 1) * 4];
                *dst = uint2{w0, w1};
            }
        }
        // ---- issue prefetch for tile t+1 (stays in flight across barrier) ----
        if (t + 1 < t1) {
            const float* kn = kgp + (size_t)(k0 + 64) * D_;
            const float* vn = vgp + (size_t)(k0 + 64) * D_;
#pragma unroll
            for (int i = 0; i < 4; ++i) kr[i] = *(const f32x4*)(kn + 4 * i);
#pragma unroll
            for (int i = 0; i < 4; ++i) vr[i] = *(const f32x4*)(vn + (size_t)i * D_);
        }
        __syncthreads();

        // ---- S^T = K * Q^T : 2 key-tiles x 4 k-steps of 32x32x16 ----
        f32x16 st[2];
#pragma unroll
        for (int ss = 0; ss < 2; ++ss) {
#pragma unroll
            for (int r = 0; r < 16; ++r) st[ss][r] = 0.f;
#pragma unroll
            for (int ks = 0; ks < 4; ++ks) {
                const int pos = (ks * 2 + h) ^ (c31 & 7);
                bf16x8 kf = *(const bf16x8*)&Kl[buf][(ss * 32 + c31) * 64 + pos * 8];
                st[ss] = __builtin_amdgcn_mfma_f32_32x32x16_bf16(
                    kf, *(const bf16x8*)&qfrag[ks][0], st[ss], 0, 0, 0);
            }
        }

        // ---- mask tail keys >= vl ----
        if (k0 + 64 > vl) {
#pragma unroll
            for (int ss = 0; ss < 2; ++ss) {
                const int base = k0 + ss * 32 + 4 * h;
#pragma unroll
                for (int r = 0; r < 16; ++r) {
                    const int key = base + (r & 3) + 8 * (r >> 2);
                    if (key >= vl) st[ss][r] = -1e30f;
                }
            }
        }

        // ---- online softmax (log2 domain), q column = c31, defer-max ----
        float tm = st[0][0];
#pragma unroll
        for (int ss = 0; ss < 2; ++ss)
#pragma unroll
            for (int r = 0; r < 16; ++r) tm = fmaxf(tm, st[ss][r]);
        tm = fmaxf(tm, __shfl_xor(tm, 32));
        if (__any(tm > mrun + 8.f)) {          // rare after the first tile
            const float mnew = fmaxf(mrun, tm);
            const float corr = exp2f(mrun - mnew);
            lrun *= corr;
#pragma unroll
            for (int dt = 0; dt < 2; ++dt)
#pragma unroll
                for (int r = 0; r < 16; ++r) oacc[dt][r] *= corr;
            mrun = mnew;
        }
        float rs = 0.f;
#pragma unroll
        for (int ss = 0; ss < 2; ++ss)
#pragma unroll
            for (int r = 0; r < 16; ++r) {
                const float p = exp2f(st[ss][r] - mrun);   // bounded by 2^8
                st[ss][r] = p;
                rs += p;
            }
        rs += __shfl_xor(rs, 32);
        lrun += rs;

        // ---- pack P to bf16 pairs ----
        unsigned pk[2][8];
#pragma unroll
        for (int ss = 0; ss < 2; ++ss)
#pragma unroll
            for (int m = 0; m < 8; ++m)
                pk[ss][m] = pk_bf16(st[ss][2 * m], st[ss][2 * m + 1]);

        // ---- O^T += V^T * P^T : 4 k-steps x 2 dim-tiles ----
#pragma unroll
        for (int kq = 0; kq < 4; ++kq) {
            const int ss = kq >> 1, A4 = (kq & 1) * 4;
            unsigned p0 = pk[ss][A4], p1 = pk[ss][A4+1], p2 = pk[ss][A4+2], p3 = pk[ss][A4+3];
            unsigned xp0 = __shfl_xor((int)p0, 32);
            unsigned xp1 = __shfl_xor((int)p1, 32);
            unsigned xp2 = __shfl_xor((int)p2, 32);
            unsigned xp3 = __shfl_xor((int)p3, 32);
            unsigned pf[4];
            pf[0] = h ? xp2 : p0;
            pf[1] = h ? xp3 : p1;
            pf[2] = h ? p2  : xp0;
            pf[3] = h ? p3  : xp1;
            const bf16x8 pfr = *(const bf16x8*)&pf[0];
#pragma unroll
            for (int dt = 0; dt < 2; ++dt) {
                const int pos = (kq * 2 + h) ^ (c31 & 7);
                bf16x8 vf = *(const bf16x8*)&Vt[buf][(dt * 32 + c31) * 64 + pos * 8];
                oacc[dt] = __builtin_amdgcn_mfma_f32_32x32x16_bf16(vf, pfr, oacc[dt], 0, 0, 0);
            }
        }
    }

    // ---- epilogue: store UNNORMALIZED partial O^T and (m, l) ----
    const size_t row = (size_t)s * (B_ * LQ_) + b * LQ_ + q0 + c31;
    float* op = OP + row * D_;
#pragma unroll
    for (int dt = 0; dt < 2; ++dt)
#pragma unroll
        for (int g = 0; g < 4; ++g) {
            f32x4 v;
#pragma unroll
            for (int j = 0; j < 4; ++j) v[j] = oacc[dt][4 * g + j];
            *(f32x4*)(op + dt * 32 + 8 * g + 4 * h) = v;
        }
    if (h == 0)
        *(float2*)&ML[row * 2] = float2{mrun, lrun};   // (-inf, 0) if empty split
}

// ---------------------------------------------------------------------------
// Pass 2: merge NS partials per q row. One thread per (row, 4-dim chunk).
// ---------------------------------------------------------------------------
template<int NS>
__global__ __launch_bounds__(256) void fa_merge_kernel(
    const float* __restrict__ OP, const float* __restrict__ ML,
    float* __restrict__ O)
{
    const int g   = blockIdx.x * 256 + threadIdx.x;   // 0 .. B*LQ*16-1
    const int row = g >> 4;                            // b*LQ + q
    const int qd  = (g & 15) * 4;

    float mf = -INFINITY;
#pragma unroll
    for (int s = 0; s < NS; ++s) {
        float2 ml = *(const float2*)&ML[((size_t)s * (B_ * LQ_) + row) * 2];
        mf = fmaxf(mf, ml.x);                          // split 0 always finite
    }
    float den = 0.f;
    f32x4 acc = {0.f, 0.f, 0.f, 0.f};
#pragma unroll
    for (int s = 0; s < NS; ++s) {
        const size_t srow = (size_t)s * (B_ * LQ_) + row;
        float2 ml = *(const float2*)&ML[srow * 2];
        const float c = exp2f(ml.x - mf);              // 0 for empty splits
        den += c * ml.y;
        f32x4 v = *(const f32x4*)&OP[srow * D_ + qd];
        acc += v * c;                                  // empty split: c=0, v=0
    }
    const float inv = 1.f / den;
    *(f32x4*)(O + (size_t)row * D_ + qd) = acc * inv;
}

// ---------------------------------------------------------------------------
// Fallback: monolithic kernel (round-3 structure + defer-max), no workspace.
// ---------------------------------------------------------------------------
__global__ __launch_bounds__(128, 2) void fa_mono_kernel(
    const float* __restrict__ Q, const float* __restrict__ K,
    const float* __restrict__ V, const int* __restrict__ vlen,
    float* __restrict__ O)
{
    __shared__ __align__(16) short Kl[2][64 * 64];
    __shared__ __align__(16) short Vt[2][64 * 64];

    const int tid  = threadIdx.x;
    const int wave = tid >> 6;
    const int lane = tid & 63;
    const int c31  = lane & 31;
    const int h    = lane >> 5;

    const int b  = blockIdx.y;
    const int q0 = blockIdx.x * 64 + wave * 32;
    const int vl = vlen[b];
    const int nt = (vl + 63) >> 6;

    const float qscale = 0.125f * 1.44269504088896340736f;

    unsigned qfrag[4][4];
#pragma unroll
    for (int ks = 0; ks < 4; ++ks) {
        const float* qp = Q + ((size_t)(b * LQ_ + q0 + c31)) * D_ + ks * 16 + h * 8;
        f32x4 t0 = *(const f32x4*)qp;
        f32x4 t1 = *(const f32x4*)(qp + 4);
#pragma unroll
        for (int jj = 0; jj < 2; ++jj) {
            qfrag[ks][jj]     = pk_bf16(t0[2*jj] * qscale, t0[2*jj+1] * qscale);
            qfrag[ks][jj + 2] = pk_bf16(t1[2*jj] * qscale, t1[2*jj+1] * qscale);
        }
    }

    f32x16 oacc[2];
#pragma unroll
    for (int dt = 0; dt < 2; ++dt)
#pragma unroll
        for (int r = 0; r < 16; ++r) oacc[dt][r] = 0.f;
    float mrun = -INFINITY, lrun = 0.f;

    const int skey = tid >> 1, skh = tid & 1;
    const int vkg = tid >> 4, vdg = tid & 15;

    const float* kgp = K + ((size_t)(b * LK_ + skey)) * D_ + skh * 32;
    const float* vgp = V + ((size_t)(b * LK_ + vkg * 8)) * D_ + vdg * 4;

    f32x4 kr[8], vr[8];
#pragma unroll
    for (int i = 0; i < 8; ++i) kr[i] = *(const f32x4*)(kgp + 4 * i);
#pragma unroll
    for (int i = 0; i < 8; ++i) vr[i] = *(const f32x4*)(vgp + (size_t)i * D_);

    for (int t = 0; t < nt; ++t) {
        const int k0 = t * 64;
        const int buf = t & 1;
        {
            unsigned pk32[16];
#pragma unroll
            for (int m = 0; m < 16; ++m)
                pk32[m] = pk_bf16(kr[m >> 1][2 * (m & 1)], kr[m >> 1][2 * (m & 1) + 1]);
#pragma unroll
            for (int cch = 0; cch < 4; ++cch) {
                const int pos = (skh * 4 + cch) ^ (skey & 7);
                *(bf16x8*)&Kl[buf][skey * 64 + pos * 8] = *(bf16x8*)&pk32[4 * cch];
            }
#pragma unroll
            for (int dr = 0; dr < 4; ++dr) {
                unsigned w[4];
#pragma unroll
                for (int p = 0; p < 4; ++p)
                    w[p] = pk_bf16(vr[2 * p][dr], vr[2 * p + 1][dr]);
                const int dim = vdg * 4 + dr;
                const int pos = vkg ^ (dim & 7);
                *(bf16x8*)&Vt[buf][dim * 64 + pos * 8] = *(bf16x8*)&w[0];
            }
        }
        if (t + 1 < nt) {
            const float* kn = kgp + (size_t)(k0 + 64) * D_;
            const float* vn = vgp + (size_t)(k0 + 64) * D_;
#pragma unroll
            for (int i = 0; i < 8; ++i) kr[i] = *(const f32x4*)(kn + 4 * i);
#pragma unroll
            for (int i = 0; i < 8; ++i) vr[i] = *(const f32x4*)(vn + (size_t)i * D_);
        }
        __syncthreads();

        f32x16 st[2];
#pragma unroll
        for (int ss = 0; ss < 2; ++ss) {
#pragma unroll
            for (int r = 0; r < 16; ++r) st[ss][r] = 0.f;
#pragma unroll
            for (int ks = 0; ks < 4; ++ks) {
                const int pos = (ks * 2 + h) ^ (c31 & 7);
                bf16x8 kf = *(const bf16x8*)&Kl[buf][(ss * 32 + c31) * 64 + pos * 8];
                st[ss] = __builtin_amdgcn_mfma_f32_32x32x16_bf16(
                    kf, *(const bf16x8*)&qfrag[ks][0], st[ss], 0, 0, 0);
            }
        }
        if (k0 + 64 > vl) {
#pragma unroll
            for (int ss = 0; ss < 2; ++ss) {
                const int base = k0 + ss * 32 + 4 * h;
#pragma unroll
                for (int r = 0; r < 16; ++r) {
                    const int key = base + (r & 3) + 8 * (r >> 2);
                    if (key >= vl) st[ss][r] = -1e30f;
                }
            }
        }
        float tm = st[0][0];
#pragma unroll
        for (int ss = 0; ss < 2; ++ss)
#pragma unroll
            for (int r = 0; r < 16; ++r) tm = fmaxf(tm, st[ss][r]);
        tm = fmaxf(tm, __shfl_xor(tm, 32));
        if (__any(tm > mrun + 8.f)) {
            const float mnew = fmaxf(mrun, tm);
            const float corr = exp2f(mrun - mnew);
            lrun *= corr;
#pragma unroll
            for (int dt = 0; dt < 2; ++dt)
#pragma unroll
                for (int r = 0; r < 16; ++r) oacc[dt][r] *= corr;
            mrun = mnew;
        }
        float rs = 0.f;
#pragma unroll
        for (int ss = 0; ss < 2; ++ss)
#pragma unroll
            for (int r = 0; r < 16; ++r) {
                const float p = exp2f(st[ss][r] - mrun);
                st[ss][r] = p;
                rs += p;
            }
        rs += __shfl_xor(rs, 32);
        lrun += rs;

        unsigned pk[2][8];
#pragma unroll
        for (int ss = 0; ss < 2; ++ss)
#pragma unroll
            for (int m = 0; m < 8; ++m)
                pk[ss][m] = pk_bf16(st[ss][2 * m], st[ss][2 * m + 1]);
#pragma unroll
        for (int kq = 0; kq < 4; ++kq) {
            const int ss = kq >> 1, A4 = (kq & 1) * 4;
            unsigned p0 = pk[ss][A4], p1 = pk[ss][A4+1], p2 = pk[ss][A4+2], p3 = pk[ss][A4+3];
            unsigned xp0 = __shfl_xor((int)p0, 32);
            unsigned xp1 = __shfl_xor((int)p1, 32);
            unsigned xp2 = __shfl_xor((int)p2, 32);
            unsigned xp3 = __shfl_xor((int)p3, 32);
            unsigned pf[4];
            pf[0] = h ? xp2 : p0;
            pf[1] = h ? xp3 : p1;
            pf[2] = h ? p2  : xp0;
            pf[3] = h ? p3  : xp1;
            const bf16x8 pfr = *(const bf16x8*)&pf[0];
#pragma unroll
            for (int dt = 0; dt < 2; ++dt) {
                const int pos = (kq * 2 + h) ^ (c31 & 7);
                bf16x8 vf = *(const bf16x8*)&Vt[buf][(dt * 32 + c31) * 64 + pos * 8];
                oacc[dt] = __builtin_amdgcn_mfma_f32_32x32x16_bf16(vf, pfr, oacc[dt], 0, 0, 0);
            }
        }
    }

    const float inv = 1.f / lrun;
    float* op = O + ((size_t)(b * LQ_ + q0 + c31)) * D_;
#pragma unroll
    for (int dt = 0; dt < 2; ++dt)
#pragma unroll
        for (int g = 0; g < 4; ++g) {
            f32x4 v;
#pragma unroll
            for (int j = 0; j < 4; ++j) v[j] = oacc[dt][4 * g + j] * inv;
            *(f32x4*)(op + dt * 32 + 8 * g + 4 * h) = v;
        }
}

extern "C" void kernel_launch(void* const* d_in, const int* in_sizes, int n_in,
                              void* d_out, int out_size, void* d_ws, size_t ws_size,
                              hipStream_t stream) {
    const float* Q    = (const float*)d_in[0];
    const float* K    = (const float*)d_in[1];
    const float* V    = (const float*)d_in[2];
    const int*   vlen = (const int*)d_in[3];
    float*       O    = (float*)d_out;

    const size_t rows = (size_t)B_ * LQ_;
    auto need = [&](int ns) { return (size_t)ns * rows * (D_ + 2) * sizeof(float); };

    int NS = 0;
    if      (d_ws && ws_size >= need(4)) NS = 4;
    else if (d_ws && ws_size >= need(2)) NS = 2;
    else if (d_ws && ws_size >= need(1)) NS = 1;

    if (NS == 0) {
        dim3 grid(LQ_ / 64, B_);
        fa_mono_kernel<<<grid, dim3(128), 0, stream>>>(Q, K, V, vlen, O);
        return;
    }

    float* OP = (float*)d_ws;
    float* ML = (float*)d_ws + (size_t)NS * rows * D_;

    dim3 g1(LQ_ / 128, B_, NS);
    fa_split2_kernel<<<g1, dim3(256), 0, stream>>>(Q, K, V, vlen, OP, ML);

    dim3 g2((unsigned)((rows * (D_ / 4)) / 256));   // 4096 blocks
    switch (NS) {
        case 4: fa_merge_kernel<4><<<g2, dim3(256), 0, stream>>>(OP, ML, O); break;
        case 2: fa_merge_kernel<2><<<g2, dim3(256), 0, stream>>>(OP, ML, O); break;
        default: fa_merge_kernel<1><<<g2, dim3(256), 0, stream>>>(OP, ML, O); break;
    }
}

// Round 6
// 158.959 us; speedup vs baseline: 1.2821x; 1.2821x over previous
//
#include <hip/hip_runtime.h>
#include <hip/hip_bf16.h>
#include <math.h>

// Masked dot-product attention, bf16 MFMA flash kernel, round 9 (= round 8
// resubmitted; round-8 bench failed on container acquisition, not the kernel).
// B=32, LQ=LK=2048, D=64. S^T = K*Q^T and O^T = V^T*P^T with 32x32x16 MFMA.
// vs round 7: ONLY the launch bound: (256,4) -> (256,2).
//  - Round-7 post-mortem: (256,4) made the compiler allocate 64 VGPRs for a
//    loop with ~80 persistent live values -> scratch spills (FETCH +109MB,
//    WRITE +67MB of spill traffic; VALUBusy 38->27 despite 2x occupancy).
//  - (256,2) is calibrated from round 5: same body compiles at ~100 VGPR ->
//    5 waves/SIMD; 32KB LDS -> 5 blocks/CU; wave cap 20/CU (2x round 6).
//  - Structure kept: 4 q-waves per block share one double-buffered 64x64 K/V
//    LDS pipeline; cross-block KV split (NS=4) + tiny merge kernel.

#define B_    32
#define LQ_   2048
#define LK_   2048
#define D_    64

typedef __attribute__((ext_vector_type(8)))  short bf16x8;
typedef __attribute__((ext_vector_type(4)))  float f32x4;
typedef __attribute__((ext_vector_type(16))) float f32x16;

static __device__ __forceinline__ unsigned pk_bf16(float a, float b) {
    __hip_bfloat162 h = __float22bfloat162_rn(float2{a, b});
    return *(unsigned*)&h;   // x in low 16 bits, y in high
}

// ---------------------------------------------------------------------------
// Pass 1: per-(qblock=128 rows, batch, split) flash attention over [t0, t1).
// 256 threads = 4 q-waves sharing one double-buffered 64x64 K/V LDS tile.
// Writes UNNORMALIZED O^T partial + (m, l) per q row.
// ---------------------------------------------------------------------------
__global__ __launch_bounds__(256, 2) void fa_split3_kernel(
    const float* __restrict__ Q, const float* __restrict__ K,
    const float* __restrict__ V, const int* __restrict__ vlen,
    float* __restrict__ OP, float* __restrict__ ML)
{
    __shared__ __align__(16) short Kl[2][64 * 64];
    __shared__ __align__(16) short Vt[2][64 * 64];

    const int tid  = threadIdx.x;          // 0..255
    const int wid  = tid >> 6;             // 0..3  (q sub-block)
    const int lane = tid & 63;
    const int c31  = lane & 31;
    const int h    = lane >> 5;

    const int b  = blockIdx.y;
    const int s  = blockIdx.z;
    const int NS = gridDim.z;
    const int q0 = blockIdx.x * 128 + wid * 32;
    const int vl = vlen[b];
    const int nt    = (vl + 63) >> 6;
    const int chunk = (nt + NS - 1) / NS;
    const int t0    = s * chunk;
    const int t1    = min(t0 + chunk, nt);

    const float qscale = 0.125f * 1.44269504088896340736f;  // 1/sqrt(64)*log2(e)

    // ---- Q B-frags in registers: B[k=dim][n=q], dim = ks*16 + h*8 + j ----
    unsigned qfrag[4][4];
#pragma unroll
    for (int ks = 0; ks < 4; ++ks) {
        const float* qp = Q + ((size_t)(b * LQ_ + q0 + c31)) * D_ + ks * 16 + h * 8;
        f32x4 t0v = *(const f32x4*)qp;
        f32x4 t1v = *(const f32x4*)(qp + 4);
#pragma unroll
        for (int jj = 0; jj < 2; ++jj) {
            qfrag[ks][jj]     = pk_bf16(t0v[2*jj] * qscale, t0v[2*jj+1] * qscale);
            qfrag[ks][jj + 2] = pk_bf16(t1v[2*jj] * qscale, t1v[2*jj+1] * qscale);
        }
    }

    f32x16 oacc[2];     // O^T acc: dim row = dt*32 + (r&3)+8*(r>>2)+4h, col q = c31
#pragma unroll
    for (int dt = 0; dt < 2; ++dt)
#pragma unroll
        for (int r = 0; r < 16; ++r) oacc[dt][r] = 0.f;
    float mrun = -INFINITY, lrun = 0.f;

    // ---- staging maps (256 threads stage the whole 64x64 K and V tiles) ----
    // K: row skey (0..63), quarter skh (0..3) of 16 floats.
    const int skey = tid >> 2, skh = tid & 3;
    // V: keys vkg*4..+3 (vkg 0..15), dims vdg*4..+3 (vdg 0..15).
    const int vkg = tid >> 4, vdg = tid & 15;

    const float* kgp = K + ((size_t)(b * LK_ + skey)) * D_ + skh * 16;
    const float* vgp = V + ((size_t)(b * LK_ + vkg * 4)) * D_ + vdg * 4;

    f32x4 kr[4], vr[4];
    // ---- prologue: prefetch tile t0 into registers ----
    if (t0 < t1) {
        const size_t off = (size_t)t0 * 64 * D_;
#pragma unroll
        for (int i = 0; i < 4; ++i) kr[i] = *(const f32x4*)(kgp + off + 4 * i);
#pragma unroll
        for (int i = 0; i < 4; ++i) vr[i] = *(const f32x4*)(vgp + off + (size_t)i * D_);
    }

    for (int t = t0; t < t1; ++t) {
        const int k0 = t * 64;
        const int buf = t & 1;

        // ---- cvt + write tile t to LDS ----
        {
            // K: 16 floats -> 8 packed pairs -> 2 swizzled b128 writes
            unsigned pk32[8];
#pragma unroll
            for (int m = 0; m < 8; ++m)
                pk32[m] = pk_bf16(kr[m >> 1][2 * (m & 1)], kr[m >> 1][2 * (m & 1) + 1]);
#pragma unroll
            for (int cch = 0; cch < 2; ++cch) {
                const int pos = (skh * 2 + cch) ^ (skey & 7);
                *(bf16x8*)&Kl[buf][skey * 64 + pos * 8] = *(bf16x8*)&pk32[4 * cch];
            }
            // V^T: 4 keys x 4 dims -> per dim one 8B write (half of a 16B chunk)
#pragma unroll
            for (int dr = 0; dr < 4; ++dr) {
                const unsigned w0 = pk_bf16(vr[0][dr], vr[1][dr]);
                const unsigned w1 = pk_bf16(vr[2][dr], vr[3][dr]);
                const int dim = vdg * 4 + dr;
                const int pos = (vkg >> 1) ^ (dim & 7);
                uint2* dst = (uint2*)&Vt[buf][dim * 64 + pos * 8 + (vkg & 1) * 4];
                *dst = uint2{w0, w1};
            }
        }
        // ---- issue prefetch for tile t+1 (stays in flight across barrier) ----
        if (t + 1 < t1) {
            const float* kn = kgp + (size_t)(k0 + 64) * D_;
            const float* vn = vgp + (size_t)(k0 + 64) * D_;
#pragma unroll
            for (int i = 0; i < 4; ++i) kr[i] = *(const f32x4*)(kn + 4 * i);
#pragma unroll
            for (int i = 0; i < 4; ++i) vr[i] = *(const f32x4*)(vn + (size_t)i * D_);
        }
        __syncthreads();

        // ---- S^T = K * Q^T : 2 key-tiles x 4 k-steps of 32x32x16 ----
        f32x16 st[2];
#pragma unroll
        for (int ss = 0; ss < 2; ++ss) {
#pragma unroll
            for (int r = 0; r < 16; ++r) st[ss][r] = 0.f;
#pragma unroll
            for (int ks = 0; ks < 4; ++ks) {
                const int pos = (ks * 2 + h) ^ (c31 & 7);
                bf16x8 kf = *(const bf16x8*)&Kl[buf][(ss * 32 + c31) * 64 + pos * 8];
                st[ss] = __builtin_amdgcn_mfma_f32_32x32x16_bf16(
                    kf, *(const bf16x8*)&qfrag[ks][0], st[ss], 0, 0, 0);
            }
        }

        // ---- mask tail keys >= vl ----
        if (k0 + 64 > vl) {
#pragma unroll
            for (int ss = 0; ss < 2; ++ss) {
                const int base = k0 + ss * 32 + 4 * h;
#pragma unroll
                for (int r = 0; r < 16; ++r) {
                    const int key = base + (r & 3) + 8 * (r >> 2);
                    if (key >= vl) st[ss][r] = -1e30f;
                }
            }
        }

        // ---- online softmax (log2 domain), q column = c31, defer-max ----
        float tm = st[0][0];
#pragma unroll
        for (int ss = 0; ss < 2; ++ss)
#pragma unroll
            for (int r = 0; r < 16; ++r) tm = fmaxf(tm, st[ss][r]);
        tm = fmaxf(tm, __shfl_xor(tm, 32));
        if (__any(tm > mrun + 8.f)) {          // rare after the first tile
            const float mnew = fmaxf(mrun, tm);
            const float corr = exp2f(mrun - mnew);
            lrun *= corr;
#pragma unroll
            for (int dt = 0; dt < 2; ++dt)
#pragma unroll
                for (int r = 0; r < 16; ++r) oacc[dt][r] *= corr;
            mrun = mnew;
        }
        float rs = 0.f;
#pragma unroll
        for (int ss = 0; ss < 2; ++ss)
#pragma unroll
            for (int r = 0; r < 16; ++r) {
                const float p = exp2f(st[ss][r] - mrun);   // bounded by 2^8
                st[ss][r] = p;
                rs += p;
            }
        rs += __shfl_xor(rs, 32);
        lrun += rs;

        // ---- pack P to bf16 pairs ----
        unsigned pk[2][8];
#pragma unroll
        for (int ss = 0; ss < 2; ++ss)
#pragma unroll
            for (int m = 0; m < 8; ++m)
                pk[ss][m] = pk_bf16(st[ss][2 * m], st[ss][2 * m + 1]);

        // ---- O^T += V^T * P^T : 4 k-steps x 2 dim-tiles ----
#pragma unroll
        for (int kq = 0; kq < 4; ++kq) {
            const int ss = kq >> 1, A4 = (kq & 1) * 4;
            unsigned p0 = pk[ss][A4], p1 = pk[ss][A4+1], p2 = pk[ss][A4+2], p3 = pk[ss][A4+3];
            unsigned xp0 = __shfl_xor((int)p0, 32);
            unsigned xp1 = __shfl_xor((int)p1, 32);
            unsigned xp2 = __shfl_xor((int)p2, 32);
            unsigned xp3 = __shfl_xor((int)p3, 32);
            unsigned pf[4];
            pf[0] = h ? xp2 : p0;
            pf[1] = h ? xp3 : p1;
            pf[2] = h ? p2  : xp0;
            pf[3] = h ? p3  : xp1;
            const bf16x8 pfr = *(const bf16x8*)&pf[0];
#pragma unroll
            for (int dt = 0; dt < 2; ++dt) {
                const int pos = (kq * 2 + h) ^ (c31 & 7);
                bf16x8 vf = *(const bf16x8*)&Vt[buf][(dt * 32 + c31) * 64 + pos * 8];
                oacc[dt] = __builtin_amdgcn_mfma_f32_32x32x16_bf16(vf, pfr, oacc[dt], 0, 0, 0);
            }
        }
    }

    // ---- epilogue: store UNNORMALIZED partial O^T and (m, l) ----
    const size_t row = (size_t)s * (B_ * LQ_) + b * LQ_ + q0 + c31;
    float* op = OP + row * D_;
#pragma unroll
    for (int dt = 0; dt < 2; ++dt)
#pragma unroll
        for (int g = 0; g < 4; ++g) {
            f32x4 v;
#pragma unroll
            for (int j = 0; j < 4; ++j) v[j] = oacc[dt][4 * g + j];
            *(f32x4*)(op + dt * 32 + 8 * g + 4 * h) = v;
        }
    if (h == 0)
        *(float2*)&ML[row * 2] = float2{mrun, lrun};   // (-inf, 0) if empty split
}

// ---------------------------------------------------------------------------
// Pass 2: merge NS partials per q row. One thread per (row, 4-dim chunk).
// ---------------------------------------------------------------------------
template<int NS>
__global__ __launch_bounds__(256) void fa_merge_kernel(
    const float* __restrict__ OP, const float* __restrict__ ML,
    float* __restrict__ O)
{
    const int g   = blockIdx.x * 256 + threadIdx.x;   // 0 .. B*LQ*16-1
    const int row = g >> 4;                            // b*LQ + q
    const int qd  = (g & 15) * 4;

    float mf = -INFINITY;
#pragma unroll
    for (int s = 0; s < NS; ++s) {
        float2 ml = *(const float2*)&ML[((size_t)s * (B_ * LQ_) + row) * 2];
        mf = fmaxf(mf, ml.x);                          // split 0 always finite
    }
    float den = 0.f;
    f32x4 acc = {0.f, 0.f, 0.f, 0.f};
#pragma unroll
    for (int s = 0; s < NS; ++s) {
        const size_t srow = (size_t)s * (B_ * LQ_) + row;
        float2 ml = *(const float2*)&ML[srow * 2];
        const float c = exp2f(ml.x - mf);              // 0 for empty splits
        den += c * ml.y;
        f32x4 v = *(const f32x4*)&OP[srow * D_ + qd];
        acc += v * c;                                  // empty split: c=0, v=0
    }
    const float inv = 1.f / den;
    *(f32x4*)(O + (size_t)row * D_ + qd) = acc * inv;
}

// ---------------------------------------------------------------------------
// Fallback: monolithic kernel (round-3 structure + defer-max), no workspace.
// ---------------------------------------------------------------------------
__global__ __launch_bounds__(128, 2) void fa_mono_kernel(
    const float* __restrict__ Q, const float* __restrict__ K,
    const float* __restrict__ V, const int* __restrict__ vlen,
    float* __restrict__ O)
{
    __shared__ __align__(16) short Kl[2][64 * 64];
    __shared__ __align__(16) short Vt[2][64 * 64];

    const int tid  = threadIdx.x;
    const int wave = tid >> 6;
    const int lane = tid & 63;
    const int c31  = lane & 31;
    const int h    = lane >> 5;

    const int b  = blockIdx.y;
    const int q0 = blockIdx.x * 64 + wave * 32;
    const int vl = vlen[b];
    const int nt = (vl + 63) >> 6;

    const float qscale = 0.125f * 1.44269504088896340736f;

    unsigned qfrag[4][4];
#pragma unroll
    for (int ks = 0; ks < 4; ++ks) {
        const float* qp = Q + ((size_t)(b * LQ_ + q0 + c31)) * D_ + ks * 16 + h * 8;
        f32x4 t0 = *(const f32x4*)qp;
        f32x4 t1 = *(const f32x4*)(qp + 4);
#pragma unroll
        for (int jj = 0; jj < 2; ++jj) {
            qfrag[ks][jj]     = pk_bf16(t0[2*jj] * qscale, t0[2*jj+1] * qscale);
            qfrag[ks][jj + 2] = pk_bf16(t1[2*jj] * qscale, t1[2*jj+1] * qscale);
        }
    }

    f32x16 oacc[2];
#pragma unroll
    for (int dt = 0; dt < 2; ++dt)
#pragma unroll
        for (int r = 0; r < 16; ++r) oacc[dt][r] = 0.f;
    float mrun = -INFINITY, lrun = 0.f;

    const int skey = tid >> 1, skh = tid & 1;
    const int vkg = tid >> 4, vdg = tid & 15;

    const float* kgp = K + ((size_t)(b * LK_ + skey)) * D_ + skh * 32;
    const float* vgp = V + ((size_t)(b * LK_ + vkg * 8)) * D_ + vdg * 4;

    f32x4 kr[8], vr[8];
#pragma unroll
    for (int i = 0; i < 8; ++i) kr[i] = *(const f32x4*)(kgp + 4 * i);
#pragma unroll
    for (int i = 0; i < 8; ++i) vr[i] = *(const f32x4*)(vgp + (size_t)i * D_);

    for (int t = 0; t < nt; ++t) {
        const int k0 = t * 64;
        const int buf = t & 1;
        {
            unsigned pk32[16];
#pragma unroll
            for (int m = 0; m < 16; ++m)
                pk32[m] = pk_bf16(kr[m >> 1][2 * (m & 1)], kr[m >> 1][2 * (m & 1) + 1]);
#pragma unroll
            for (int cch = 0; cch < 4; ++cch) {
                const int pos = (skh * 4 + cch) ^ (skey & 7);
                *(bf16x8*)&Kl[buf][skey * 64 + pos * 8] = *(bf16x8*)&pk32[4 * cch];
            }
#pragma unroll
            for (int dr = 0; dr < 4; ++dr) {
                unsigned w[4];
#pragma unroll
                for (int p = 0; p < 4; ++p)
                    w[p] = pk_bf16(vr[2 * p][dr], vr[2 * p + 1][dr]);
                const int dim = vdg * 4 + dr;
                const int pos = vkg ^ (dim & 7);
                *(bf16x8*)&Vt[buf][dim * 64 + pos * 8] = *(bf16x8*)&w[0];
            }
        }
        if (t + 1 < nt) {
            const float* kn = kgp + (size_t)(k0 + 64) * D_;
            const float* vn = vgp + (size_t)(k0 + 64) * D_;
#pragma unroll
            for (int i = 0; i < 8; ++i) kr[i] = *(const f32x4*)(kn + 4 * i);
#pragma unroll
            for (int i = 0; i < 8; ++i) vr[i] = *(const f32x4*)(vn + (size_t)i * D_);
        }
        __syncthreads();

        f32x16 st[2];
#pragma unroll
        for (int ss = 0; ss < 2; ++ss) {
#pragma unroll
            for (int r = 0; r < 16; ++r) st[ss][r] = 0.f;
#pragma unroll
            for (int ks = 0; ks < 4; ++ks) {
                const int pos = (ks * 2 + h) ^ (c31 & 7);
                bf16x8 kf = *(const bf16x8*)&Kl[buf][(ss * 32 + c31) * 64 + pos * 8];
                st[ss] = __builtin_amdgcn_mfma_f32_32x32x16_bf16(
                    kf, *(const bf16x8*)&qfrag[ks][0], st[ss], 0, 0, 0);
            }
        }
        if (k0 + 64 > vl) {
#pragma unroll
            for (int ss = 0; ss < 2; ++ss) {
                const int base = k0 + ss * 32 + 4 * h;
#pragma unroll
                for (int r = 0; r < 16; ++r) {
                    const int key = base + (r & 3) + 8 * (r >> 2);
                    if (key >= vl) st[ss][r] = -1e30f;
                }
            }
        }
        float tm = st[0][0];
#pragma unroll
        for (int ss = 0; ss < 2; ++ss)
#pragma unroll
            for (int r = 0; r < 16; ++r) tm = fmaxf(tm, st[ss][r]);
        tm = fmaxf(tm, __shfl_xor(tm, 32));
        if (__any(tm > mrun + 8.f)) {
            const float mnew = fmaxf(mrun, tm);
            const float corr = exp2f(mrun - mnew);
            lrun *= corr;
#pragma unroll
            for (int dt = 0; dt < 2; ++dt)
#pragma unroll
                for (int r = 0; r < 16; ++r) oacc[dt][r] *= corr;
            mrun = mnew;
        }
        float rs = 0.f;
#pragma unroll
        for (int ss = 0; ss < 2; ++ss)
#pragma unroll
            for (int r = 0; r < 16; ++r) {
                const float p = exp2f(st[ss][r] - mrun);
                st[ss][r] = p;
                rs += p;
            }
        rs += __shfl_xor(rs, 32);
        lrun += rs;

        unsigned pk[2][8];
#pragma unroll
        for (int ss = 0; ss < 2; ++ss)
#pragma unroll
            for (int m = 0; m < 8; ++m)
                pk[ss][m] = pk_bf16(st[ss][2 * m], st[ss][2 * m + 1]);
#pragma unroll
        for (int kq = 0; kq < 4; ++kq) {
            const int ss = kq >> 1, A4 = (kq & 1) * 4;
            unsigned p0 = pk[ss][A4], p1 = pk[ss][A4+1], p2 = pk[ss][A4+2], p3 = pk[ss][A4+3];
            unsigned xp0 = __shfl_xor((int)p0, 32);
            unsigned xp1 = __shfl_xor((int)p1, 32);
            unsigned xp2 = __shfl_xor((int)p2, 32);
            unsigned xp3 = __shfl_xor((int)p3, 32);
            unsigned pf[4];
            pf[0] = h ? xp2 : p0;
            pf[1] = h ? xp3 : p1;
            pf[2] = h ? p2  : xp0;
            pf[3] = h ? p3  : xp1;
            const bf16x8 pfr = *(const bf16x8*)&pf[0];
#pragma unroll
            for (int dt = 0; dt < 2; ++dt) {
                const int pos = (kq * 2 + h) ^ (c31 & 7);
                bf16x8 vf = *(const bf16x8*)&Vt[buf][(dt * 32 + c31) * 64 + pos * 8];
                oacc[dt] = __builtin_amdgcn_mfma_f32_32x32x16_bf16(vf, pfr, oacc[dt], 0, 0, 0);
            }
        }
    }

    const float inv = 1.f / lrun;
    float* op = O + ((size_t)(b * LQ_ + q0 + c31)) * D_;
#pragma unroll
    for (int dt = 0; dt < 2; ++dt)
#pragma unroll
        for (int g = 0; g < 4; ++g) {
            f32x4 v;
#pragma unroll
            for (int j = 0; j < 4; ++j) v[j] = oacc[dt][4 * g + j] * inv;
            *(f32x4*)(op + dt * 32 + 8 * g + 4 * h) = v;
        }
}

extern "C" void kernel_launch(void* const* d_in, const int* in_sizes, int n_in,
                              void* d_out, int out_size, void* d_ws, size_t ws_size,
                              hipStream_t stream) {
    const float* Q    = (const float*)d_in[0];
    const float* K    = (const float*)d_in[1];
    const float* V    = (const float*)d_in[2];
    const int*   vlen = (const int*)d_in[3];
    float*       O    = (float*)d_out;

    const size_t rows = (size_t)B_ * LQ_;
    auto need = [&](int ns) { return (size_t)ns * rows * (D_ + 2) * sizeof(float); };

    int NS = 0;
    if      (d_ws && ws_size >= need(4)) NS = 4;
    else if (d_ws && ws_size >= need(2)) NS = 2;
    else if (d_ws && ws_size >= need(1)) NS = 1;

    if (NS == 0) {
        dim3 grid(LQ_ / 64, B_);
        fa_mono_kernel<<<grid, dim3(128), 0, stream>>>(Q, K, V, vlen, O);
        return;
    }

    float* OP = (float*)d_ws;
    float* ML = (float*)d_ws + (size_t)NS * rows * D_;

    dim3 g1(LQ_ / 128, B_, NS);
    fa_split3_kernel<<<g1, dim3(256), 0, stream>>>(Q, K, V, vlen, OP, ML);

    dim3 g2((unsigned)((rows * (D_ / 4)) / 256));   // 4096 blocks
    switch (NS) {
        case 4: fa_merge_kernel<4><<<g2, dim3(256), 0, stream>>>(OP, ML, O); break;
        case 2: fa_merge_kernel<2><<<g2, dim3(256), 0, stream>>>(OP, ML, O); break;
        default: fa_merge_kernel<1><<<g2, dim3(256), 0, stream>>>(OP, ML, O); break;
    }
}